// Round 5
// baseline (660.880 us; speedup 1.0000x reference)
//
#include <hip/hip_runtime.h>
#include <math.h>

#define N_NODES 100000
#define N_EDGES 1600000
#define IN_CH 512
#define HID 128
#define OUT_CH 64
#define NBUCK ((N_NODES + 255) / 256)  // 391
#define LBUF_CAP 8192

typedef __attribute__((ext_vector_type(8))) short bf16x8;
typedef __attribute__((ext_vector_type(4))) float f32x4;

__device__ __forceinline__ float gelu_exact(float v) {
    return 0.5f * v * (1.0f + erff(v * 0.70710678118654752440f));
}

__device__ __forceinline__ unsigned short bf16r(float f) {
    union { float f; unsigned int u; } v;
    v.f = f;
    unsigned int r = v.u + 0x7fffu + ((v.u >> 16) & 1u);
    return (unsigned short)(r >> 16);
}

__device__ __forceinline__ float bf16f(unsigned short h) {
    union { unsigned int u; float f; } v;
    v.u = ((unsigned int)h) << 16;
    return v.f;
}

// ---------------- bucketed CSR build ----------------
__global__ void bzero(int* __restrict__ bcnt) {
    if (threadIdx.x < NBUCK) bcnt[threadIdx.x] = 0;
}

__global__ __launch_bounds__(256) void bhist(const int* __restrict__ dst,
                                             int* __restrict__ bcnt, int e) {
    __shared__ int lcnt[NBUCK];
    for (int i = threadIdx.x; i < NBUCK; i += 256) lcnt[i] = 0;
    __syncthreads();
    int base = blockIdx.x * 256 * 16 + threadIdx.x;
#pragma unroll
    for (int i = 0; i < 16; i++) {
        int id = base + i * 256;
        if (id < e) atomicAdd(&lcnt[dst[id] >> 8], 1);
    }
    __syncthreads();
    for (int i = threadIdx.x; i < NBUCK; i += 256)
        if (lcnt[i]) atomicAdd(&bcnt[i], lcnt[i]);
}

__global__ void bscan(const int* __restrict__ bcnt, int* __restrict__ bbase,
                      int* __restrict__ bcur, int* __restrict__ rowptr, int e) {
    __shared__ int tmp[512];
    int i = threadIdx.x;
    int v = (i < NBUCK) ? bcnt[i] : 0;
    tmp[i] = v;
    __syncthreads();
#pragma unroll
    for (int o = 1; o < 512; o <<= 1) {
        int t = (i >= o) ? tmp[i - o] : 0;
        __syncthreads();
        tmp[i] += t;
        __syncthreads();
    }
    if (i <= NBUCK) {
        int excl = (i == 0) ? 0 : tmp[i - 1];
        bbase[i] = excl;
        if (i < NBUCK) bcur[i] = excl;
    }
    if (i == 0) rowptr[N_NODES] = e;
}

// pass A: bin edges into bucket-segmented ebuf, packed (src<<8)|local_dst
__global__ __launch_bounds__(256) void binA(const int* __restrict__ src,
                                            const int* __restrict__ dst,
                                            int* __restrict__ bcur,
                                            unsigned int* __restrict__ ebuf, int e) {
    __shared__ int lcnt[NBUCK];
    __shared__ int gbase[NBUCK];
    const int tid = threadIdx.x;
    for (int i = tid; i < NBUCK; i += 256) lcnt[i] = 0;
    __syncthreads();
    const int base = blockIdx.x * (256 * 16);
    int sv[16];
    short bk[16], rk[16];
    unsigned char ld[16];
#pragma unroll
    for (int i = 0; i < 16; i++) {
        int idx = base + tid + i * 256;
        bk[i] = -1;
        if (idx < e) {
            int d = dst[idx];
            sv[i] = src[idx];
            ld[i] = (unsigned char)(d & 255);
            int b = d >> 8;
            bk[i] = (short)b;
            rk[i] = (short)atomicAdd(&lcnt[b], 1);
        }
    }
    __syncthreads();
    for (int i = tid; i < NBUCK; i += 256)
        if (lcnt[i]) gbase[i] = atomicAdd(&bcur[i], lcnt[i]);
    __syncthreads();
#pragma unroll
    for (int i = 0; i < 16; i++)
        if (bk[i] >= 0)
            ebuf[gbase[bk[i]] + rk[i]] = ((unsigned int)sv[i] << 8) | ld[i];
}

// pass B: per bucket -> local CSR (rowptr, dinv) + coalesced eadj
__global__ __launch_bounds__(256) void binB(const unsigned int* __restrict__ ebuf,
                                            const int* __restrict__ bbase,
                                            int* __restrict__ rowptr, int* __restrict__ eadj,
                                            float* __restrict__ dinv) {
    __shared__ int cnt[256], lofs[256], lcur[256];
    __shared__ int lbuf[LBUF_CAP];
    const int b = blockIdx.x, tid = threadIdx.x;
    const int n0 = b * 256;
    const int nn = min(256, N_NODES - n0);
    const int e0 = bbase[b], e1 = bbase[b + 1];
    const int ecount = e1 - e0;
    cnt[tid] = 0;
    __syncthreads();
    for (int i = tid; i < ecount; i += 256) atomicAdd(&cnt[ebuf[e0 + i] & 255], 1);
    __syncthreads();
    int v = cnt[tid];
    lofs[tid] = v;
    __syncthreads();
#pragma unroll
    for (int o = 1; o < 256; o <<= 1) {
        int t = (tid >= o) ? lofs[tid - o] : 0;
        __syncthreads();
        lofs[tid] += t;
        __syncthreads();
    }
    int excl = lofs[tid] - v;
    lcur[tid] = excl;
    if (tid < nn) {
        rowptr[n0 + tid] = e0 + excl;
        dinv[n0 + tid] = rsqrtf((float)(v + 1));
    }
    __syncthreads();
    for (int i = tid; i < ecount; i += 256) {
        unsigned int w = ebuf[e0 + i];
        int pos = atomicAdd(&lcur[w & 255], 1);
        int s = (int)(w >> 8);
        if (pos < LBUF_CAP) lbuf[pos] = s;
        else eadj[e0 + pos] = s;  // overflow safety (never expected: avg 4092/bucket)
    }
    __syncthreads();
    int lim = min(ecount, LBUF_CAP);
    for (int i = tid; i < lim; i += 256) eadj[e0 + i] = lbuf[i];
}

// ---------------- weight transpose+convert, all three mats in one launch ----------------
// out[n][k] = bf16(in[k][n])
__global__ __launch_bounds__(256) void conv_all(const float* __restrict__ W1,
                                                const float* __restrict__ Wc,
                                                const float* __restrict__ W2,
                                                unsigned short* __restrict__ W1T,
                                                unsigned short* __restrict__ WcT,
                                                unsigned short* __restrict__ W2T) {
    int idx = blockIdx.x * 256 + threadIdx.x;
    if (idx < IN_CH * HID) {
        int n = idx / IN_CH, k = idx % IN_CH;
        W1T[idx] = bf16r(W1[(size_t)k * HID + n]);
        return;
    }
    idx -= IN_CH * HID;
    if (idx < HID * HID) {
        int n = idx / HID, k = idx % HID;
        WcT[idx] = bf16r(Wc[(size_t)k * HID + n]);
        return;
    }
    idx -= HID * HID;
    if (idx < HID * OUT_CH) {
        int n = idx / HID, k = idx % HID;
        W2T[idx] = bf16r(W2[(size_t)k * OUT_CH + n]);
    }
}

// ---------------- MFMA GEMM (BM=64, dbuf LDS, XOR swizzle) ----------------
// SCALE: multiply the LN output by dinvp[row] before storing (pre-folds the
// symmetric normalization into the gather input rows).
template <int K, int NT, bool A32, bool LN, bool SCALE>
__global__ __launch_bounds__(256) void gemm_mfma(
    const void* __restrict__ Aptr, const unsigned short* __restrict__ BT,
    const float* __restrict__ bias, const float* __restrict__ gamma,
    const float* __restrict__ beta, const float* __restrict__ dinvp,
    void* __restrict__ Cptr, int M) {
    constexpr int BM = 64, N = NT * 16, NSTEP = K / 32;
    __shared__ unsigned short As[2][BM * 32];
    __shared__ unsigned short Bs[2][N * 32];
    const int tid = threadIdx.x;
    const int wave = tid >> 6, lane = tid & 63;
    const int l15 = lane & 15, quad = lane >> 4;
    const int row0 = blockIdx.x * BM;

    const int sr = tid >> 2, sc = tid & 3;
    const int sswz = sc ^ ((sr >> 2) & 3);
    const bool aok = (row0 + sr) < M;

    const float* A32p = (const float*)Aptr + (size_t)(row0 + sr) * K + sc * 8;
    const unsigned short* A16p = (const unsigned short*)Aptr + (size_t)(row0 + sr) * K + sc * 8;
    const unsigned short* B0p = BT + (size_t)sr * K + sc * 8;
    const unsigned short* B1p = BT + (size_t)(sr + 64) * K + sc * 8;

    float4 pa0, pa1;
    int4 pa16, pb0, pb1;
    if (A32) {
        pa0 = aok ? *(const float4*)(A32p) : make_float4(0.f, 0.f, 0.f, 0.f);
        pa1 = aok ? *(const float4*)(A32p + 4) : make_float4(0.f, 0.f, 0.f, 0.f);
    } else {
        pa16 = aok ? *(const int4*)(A16p) : make_int4(0, 0, 0, 0);
    }
    pb0 = *(const int4*)(B0p);
    if (NT == 8) pb1 = *(const int4*)(B1p);

    f32x4 acc[NT];
#pragma unroll
    for (int ni = 0; ni < NT; ni++) acc[ni] = (f32x4){0.f, 0.f, 0.f, 0.f};

    float bia[NT], gam[NT], bet[NT];
#pragma unroll
    for (int ni = 0; ni < NT; ni++) {
        bia[ni] = bias[ni * 16 + l15];
        if (LN) {
            gam[ni] = gamma[ni * 16 + l15];
            bet[ni] = beta[ni * 16 + l15];
        }
    }

    const int fswz = quad ^ ((l15 >> 2) & 3);
    const int aoff = (wave * 16 + l15) * 32 + fswz * 8;

    for (int step = 0; step < NSTEP; step++) {
        const int buf = step & 1;
        if (A32) {
            int4 w;
            w.x = (int)((unsigned int)bf16r(pa0.x) | ((unsigned int)bf16r(pa0.y) << 16));
            w.y = (int)((unsigned int)bf16r(pa0.z) | ((unsigned int)bf16r(pa0.w) << 16));
            w.z = (int)((unsigned int)bf16r(pa1.x) | ((unsigned int)bf16r(pa1.y) << 16));
            w.w = (int)((unsigned int)bf16r(pa1.z) | ((unsigned int)bf16r(pa1.w) << 16));
            *(int4*)&As[buf][sr * 32 + sswz * 8] = w;
        } else {
            *(int4*)&As[buf][sr * 32 + sswz * 8] = pa16;
        }
        *(int4*)&Bs[buf][sr * 32 + sswz * 8] = pb0;
        if (NT == 8) *(int4*)&Bs[buf][(sr + 64) * 32 + sswz * 8] = pb1;
        __syncthreads();
        if (step + 1 < NSTEP) {
            const int ko = (step + 1) * 32;
            if (A32) {
                pa0 = aok ? *(const float4*)(A32p + ko) : make_float4(0.f, 0.f, 0.f, 0.f);
                pa1 = aok ? *(const float4*)(A32p + ko + 4) : make_float4(0.f, 0.f, 0.f, 0.f);
            } else {
                pa16 = aok ? *(const int4*)(A16p + ko) : make_int4(0, 0, 0, 0);
            }
            pb0 = *(const int4*)(B0p + ko);
            if (NT == 8) pb1 = *(const int4*)(B1p + ko);
        }
        bf16x8 a = *(const bf16x8*)&As[buf][aoff];
#pragma unroll
        for (int ni = 0; ni < NT; ni++) {
            bf16x8 b = *(const bf16x8*)&Bs[buf][(ni * 16 + l15) * 32 + fswz * 8];
            acc[ni] = __builtin_amdgcn_mfma_f32_16x16x32_bf16(a, b, acc[ni], 0, 0, 0);
        }
    }

#pragma unroll
    for (int r = 0; r < 4; r++) {
        int grow = row0 + wave * 16 + quad * 4 + r;
        if (LN) {
            float g[NT];
            float s = 0.f, sq = 0.f;
#pragma unroll
            for (int ni = 0; ni < NT; ni++) {
                float v = gelu_exact(acc[ni][r] + bia[ni]);
                g[ni] = v;
                s += v;
                sq += v * v;
            }
#pragma unroll
            for (int m = 1; m < 16; m <<= 1) {
                s += __shfl_xor(s, m);
                sq += __shfl_xor(sq, m);
            }
            float mu = s * (1.0f / N);
            float var = sq * (1.0f / N) - mu * mu;
            float rs = rsqrtf(var + 1e-5f);
            if (grow < M) {
                float dv = 1.0f;
                if (SCALE) dv = dinvp[grow];
                unsigned short* C = (unsigned short*)Cptr;
#pragma unroll
                for (int ni = 0; ni < NT; ni++) {
                    float o = (g[ni] - mu) * rs * gam[ni] + bet[ni];
                    if (SCALE) o *= dv;
                    C[(size_t)grow * N + ni * 16 + l15] = bf16r(o);
                }
            }
        } else {
            if (grow < M) {
                float* C = (float*)Cptr;
#pragma unroll
                for (int ni = 0; ni < NT; ni++)
                    C[(size_t)grow * N + ni * 16 + l15] = acc[ni][r] + bia[ni];
            }
        }
    }
}

// ---------------- propagation: add-only CSR gather on pre-scaled bf16 rows ----------------
// Input rows are h' = dinv[j]*h[j].  out[i] = scale(i) * (h'[i] + sum_{j in N(i)} h'[j])
// where scale = dinv^2 for hop1 (output stays pre-scaled for hop2) and dinv for hop2.
// REP > 1 is a timing probe only: re-walks the edge list REP times (asm barrier
// prevents cross-rep load CSE) so the dispatch exceeds the fill duration and
// surfaces in the top-5 counter table with its own PMC row.
template <int REP, int PW>
__global__ __launch_bounds__(256) void sgc_gather_bf16(const unsigned short* __restrict__ hin,
                                                       unsigned short* __restrict__ hout,
                                                       const int* __restrict__ rowptr,
                                                       const int* __restrict__ eadj,
                                                       const float* __restrict__ dinv,
                                                       int n) {
    int row = __builtin_amdgcn_readfirstlane(blockIdx.x * 4 + (threadIdx.x >> 6));
    if (row >= n) return;
    const int lane = threadIdx.x & 63;
    const unsigned int* __restrict__ rows = (const unsigned int*)hin;
    // self term (pre-scaled row)
    unsigned int u = rows[(size_t)row * 64 + lane];
    float ax = bf16f((unsigned short)(u & 0xffff));
    float ay = bf16f((unsigned short)(u >> 16));
    for (int rep = 0; rep < REP; rep++) {
        int j = rowptr[row];
        const int end = rowptr[row + 1];
        for (; j + 7 < end; j += 8) {
            int s[8];
#pragma unroll
            for (int t = 0; t < 8; t++) s[t] = __builtin_amdgcn_readfirstlane(eadj[j + t]);
            unsigned int uu[8];
#pragma unroll
            for (int t = 0; t < 8; t++) uu[t] = rows[(size_t)s[t] * 64 + lane];
#pragma unroll
            for (int t = 0; t < 8; t++) {
                ax += bf16f((unsigned short)(uu[t] & 0xffff));
                ay += bf16f((unsigned short)(uu[t] >> 16));
            }
        }
        for (; j < end; j++) {
            int s0 = __builtin_amdgcn_readfirstlane(eadj[j]);
            unsigned int u0 = rows[(size_t)s0 * 64 + lane];
            ax += bf16f((unsigned short)(u0 & 0xffff));
            ay += bf16f((unsigned short)(u0 >> 16));
        }
        if (REP > 1) asm volatile("" : "+v"(ax), "+v"(ay));  // keep reps live, no CSE
    }
    float di = dinv[row];
    float sc = (PW == 2) ? di * di : di;
    ax *= sc;
    ay *= sc;
    unsigned int o = (unsigned int)bf16r(ax) | ((unsigned int)bf16r(ay) << 16);
    *(unsigned int*)(hout + (size_t)row * HID + lane * 2) = o;
}

extern "C" void kernel_launch(void* const* d_in, const int* in_sizes, int n_in,
                              void* d_out, int out_size, void* d_ws, size_t ws_size,
                              hipStream_t stream) {
    const float* x   = (const float*)d_in[0];
    const int*   ei  = (const int*)d_in[1];
    const float* W1  = (const float*)d_in[2];
    const float* b1  = (const float*)d_in[3];
    const float* g1  = (const float*)d_in[4];
    const float* be1 = (const float*)d_in[5];
    const float* Wc  = (const float*)d_in[6];
    const float* bc  = (const float*)d_in[7];
    const float* g2  = (const float*)d_in[8];
    const float* be2 = (const float*)d_in[9];
    const float* W2  = (const float*)d_in[10];
    const float* b2  = (const float*)d_in[11];
    float* out = (float*)d_out;

    const int N = in_sizes[0] / IN_CH;  // 100000
    const int E = in_sizes[1] / 2;      // 1600000
    const int* src = ei;
    const int* dst = ei + E;

    char* ws = (char*)d_ws;
    size_t off = 0;
    auto alloc = [&](size_t bytes) {
        void* p = ws + off;
        off = (off + bytes + 255) & ~(size_t)255;
        return p;
    };
    float* dinv   = (float*)alloc((size_t)N * 4);
    int*   rowptr = (int*)alloc((size_t)(N + 1) * 4);
    int*   bcnt   = (int*)alloc((size_t)(NBUCK + 1) * 4);
    int*   bbase  = (int*)alloc((size_t)(NBUCK + 1) * 4);
    int*   bcur   = (int*)alloc((size_t)(NBUCK + 1) * 4);
    unsigned int* ebuf = (unsigned int*)alloc((size_t)E * 4);
    int*   eadj   = (int*)alloc((size_t)E * 4);
    unsigned short* W1T = (unsigned short*)alloc((size_t)HID * IN_CH * 2);
    unsigned short* WcT = (unsigned short*)alloc((size_t)HID * HID * 2);
    unsigned short* W2T = (unsigned short*)alloc((size_t)OUT_CH * HID * 2);
    unsigned short* hA  = (unsigned short*)alloc((size_t)N * HID * 2);
    unsigned short* hB  = (unsigned short*)alloc((size_t)N * HID * 2);
    unsigned short* hScr = (unsigned short*)alloc((size_t)N * HID * 2);  // probe sink

    const int B = 256;
    const int eblk16 = (E + 4095) / 4096;  // 391

    // bucketed CSR build (+ dinv, rowptr)
    bzero<<<1, 512, 0, stream>>>(bcnt);
    bhist<<<eblk16, B, 0, stream>>>(dst, bcnt, E);
    bscan<<<1, 512, 0, stream>>>(bcnt, bbase, bcur, rowptr, E);
    binA<<<eblk16, B, 0, stream>>>(src, dst, bcur, ebuf, E);
    binB<<<NBUCK, B, 0, stream>>>(ebuf, bbase, rowptr, eadj, dinv);

    // weight prep (single launch)
    const int convtot = IN_CH * HID + HID * HID + HID * OUT_CH;
    conv_all<<<(convtot + 255) / 256, B, 0, stream>>>(W1, Wc, W2, W1T, WcT, W2T);

    const int gblk = (N + 63) / 64;  // 1563
    // lin1 + gelu + LN + dinv-prescale -> hA (bf16, rows = dinv*h)
    gemm_mfma<IN_CH, 8, true, true, true><<<gblk, B, 0, stream>>>(x, W1T, b1, g1, be1, dinv, hA, N);
    // hops (add-only): hA -> hB (x dinv^2, stays pre-scaled) -> hA (x dinv, unscaled h2)
    sgc_gather_bf16<1, 2><<<(N + 3) / 4, B, 0, stream>>>(hA, hB, rowptr, eadj, dinv, N);
    sgc_gather_bf16<1, 1><<<(N + 3) / 4, B, 0, stream>>>(hB, hA, rowptr, eadj, dinv, N);
    // Wc + gelu + LN -> hB (bf16)
    gemm_mfma<HID, 8, false, true, false><<<gblk, B, 0, stream>>>(hA, WcT, bc, g2, be2, nullptr, hB, N);
    // W2 + bias -> out (fp32)
    gemm_mfma<HID, 4, false, false, false><<<gblk, B, 0, stream>>>(hB, W2T, b2, nullptr, nullptr, nullptr, out, N);

    // ---- timing probe (diagnostic only, writes to scratch): 4x-work gather ----
    sgc_gather_bf16<4, 1><<<(N + 3) / 4, B, 0, stream>>>(hA, hScr, rowptr, eadj, dinv, N);
}

// Round 6
// 527.199 us; speedup vs baseline: 1.2536x; 1.2536x over previous
//
#include <hip/hip_runtime.h>
#include <math.h>

#define N_NODES 100000
#define N_EDGES 1600000
#define IN_CH 512
#define HID 128
#define OUT_CH 64
#define NBUCK ((N_NODES + 255) / 256)  // 391
#define LBUF_CAP 8192

typedef __attribute__((ext_vector_type(8))) short bf16x8;
typedef __attribute__((ext_vector_type(4))) float f32x4;

__device__ __forceinline__ float gelu_exact(float v) {
    return 0.5f * v * (1.0f + erff(v * 0.70710678118654752440f));
}

__device__ __forceinline__ unsigned short bf16r(float f) {
    union { float f; unsigned int u; } v;
    v.f = f;
    unsigned int r = v.u + 0x7fffu + ((v.u >> 16) & 1u);
    return (unsigned short)(r >> 16);
}

__device__ __forceinline__ float bf16f(unsigned short h) {
    union { unsigned int u; float f; } v;
    v.u = ((unsigned int)h) << 16;
    return v.f;
}

// ---------------- bucketed CSR build ----------------
__global__ __launch_bounds__(256) void bhist(const int* __restrict__ dst,
                                             int* __restrict__ bcnt, int e) {
    __shared__ int lcnt[NBUCK];
    for (int i = threadIdx.x; i < NBUCK; i += 256) lcnt[i] = 0;
    __syncthreads();
    int base = blockIdx.x * 256 * 16 + threadIdx.x;
#pragma unroll
    for (int i = 0; i < 16; i++) {
        int id = base + i * 256;
        if (id < e) atomicAdd(&lcnt[dst[id] >> 8], 1);
    }
    __syncthreads();
    for (int i = threadIdx.x; i < NBUCK; i += 256)
        if (lcnt[i]) atomicAdd(&bcnt[i], lcnt[i]);
}

__global__ void bscan(const int* __restrict__ bcnt, int* __restrict__ bbase,
                      int* __restrict__ bcur, int* __restrict__ rowptr, int e) {
    __shared__ int tmp[512];
    int i = threadIdx.x;
    int v = (i < NBUCK) ? bcnt[i] : 0;
    tmp[i] = v;
    __syncthreads();
#pragma unroll
    for (int o = 1; o < 512; o <<= 1) {
        int t = (i >= o) ? tmp[i - o] : 0;
        __syncthreads();
        tmp[i] += t;
        __syncthreads();
    }
    if (i <= NBUCK) {
        int excl = (i == 0) ? 0 : tmp[i - 1];
        bbase[i] = excl;
        if (i < NBUCK) bcur[i] = excl;
    }
    if (i == 0) rowptr[N_NODES] = e;
}

// pass A: bin edges into bucket-segmented ebuf, packed (src<<8)|local_dst
__global__ __launch_bounds__(256) void binA(const int* __restrict__ src,
                                            const int* __restrict__ dst,
                                            int* __restrict__ bcur,
                                            unsigned int* __restrict__ ebuf, int e) {
    __shared__ int lcnt[NBUCK];
    __shared__ int gbase[NBUCK];
    const int tid = threadIdx.x;
    for (int i = tid; i < NBUCK; i += 256) lcnt[i] = 0;
    __syncthreads();
    const int base = blockIdx.x * (256 * 16);
    int sv[16];
    short bk[16], rk[16];
    unsigned char ld[16];
#pragma unroll
    for (int i = 0; i < 16; i++) {
        int idx = base + tid + i * 256;
        bk[i] = -1;
        if (idx < e) {
            int d = dst[idx];
            sv[i] = src[idx];
            ld[i] = (unsigned char)(d & 255);
            int b = d >> 8;
            bk[i] = (short)b;
            rk[i] = (short)atomicAdd(&lcnt[b], 1);
        }
    }
    __syncthreads();
    for (int i = tid; i < NBUCK; i += 256)
        if (lcnt[i]) gbase[i] = atomicAdd(&bcur[i], lcnt[i]);
    __syncthreads();
#pragma unroll
    for (int i = 0; i < 16; i++)
        if (bk[i] >= 0)
            ebuf[gbase[bk[i]] + rk[i]] = ((unsigned int)sv[i] << 8) | ld[i];
}

// pass B: per bucket -> local CSR (rowptr, dinv) + coalesced eadj
__global__ __launch_bounds__(256) void binB(const unsigned int* __restrict__ ebuf,
                                            const int* __restrict__ bbase,
                                            int* __restrict__ rowptr, int* __restrict__ eadj,
                                            float* __restrict__ dinv) {
    __shared__ int cnt[256], lofs[256], lcur[256];
    __shared__ int lbuf[LBUF_CAP];
    const int b = blockIdx.x, tid = threadIdx.x;
    const int n0 = b * 256;
    const int nn = min(256, N_NODES - n0);
    const int e0 = bbase[b], e1 = bbase[b + 1];
    const int ecount = e1 - e0;
    cnt[tid] = 0;
    __syncthreads();
    for (int i = tid; i < ecount; i += 256) atomicAdd(&cnt[ebuf[e0 + i] & 255], 1);
    __syncthreads();
    int v = cnt[tid];
    lofs[tid] = v;
    __syncthreads();
#pragma unroll
    for (int o = 1; o < 256; o <<= 1) {
        int t = (tid >= o) ? lofs[tid - o] : 0;
        __syncthreads();
        lofs[tid] += t;
        __syncthreads();
    }
    int excl = lofs[tid] - v;
    lcur[tid] = excl;
    if (tid < nn) {
        rowptr[n0 + tid] = e0 + excl;
        dinv[n0 + tid] = rsqrtf((float)(v + 1));
    }
    __syncthreads();
    for (int i = tid; i < ecount; i += 256) {
        unsigned int w = ebuf[e0 + i];
        int pos = atomicAdd(&lcur[w & 255], 1);
        int s = (int)(w >> 8);
        if (pos < LBUF_CAP) lbuf[pos] = s;
        else eadj[e0 + pos] = s;  // overflow safety (never expected: avg 4092/bucket)
    }
    __syncthreads();
    int lim = min(ecount, LBUF_CAP);
    for (int i = tid; i < lim; i += 256) eadj[e0 + i] = lbuf[i];
}

// ---------------- weight transpose+convert (all three) + bcnt zero, one launch ----------
// out[n][k] = bf16(in[k][n]).  Runs FIRST; block 0 also zeroes bcnt for bhist.
__global__ __launch_bounds__(256) void conv_all(const float* __restrict__ W1,
                                                const float* __restrict__ Wc,
                                                const float* __restrict__ W2,
                                                unsigned short* __restrict__ W1T,
                                                unsigned short* __restrict__ WcT,
                                                unsigned short* __restrict__ W2T,
                                                int* __restrict__ bcnt) {
    if (blockIdx.x == 0)
        for (int i = threadIdx.x; i < NBUCK; i += 256) bcnt[i] = 0;
    int idx = blockIdx.x * 256 + threadIdx.x;
    if (idx < IN_CH * HID) {
        int n = idx / IN_CH, k = idx % IN_CH;
        W1T[idx] = bf16r(W1[(size_t)k * HID + n]);
        return;
    }
    idx -= IN_CH * HID;
    if (idx < HID * HID) {
        int n = idx / HID, k = idx % HID;
        WcT[idx] = bf16r(Wc[(size_t)k * HID + n]);
        return;
    }
    idx -= HID * HID;
    if (idx < HID * OUT_CH) {
        int n = idx / HID, k = idx % HID;
        W2T[idx] = bf16r(W2[(size_t)k * OUT_CH + n]);
    }
}

// ---------------- MFMA GEMM (BM=64, dbuf LDS, XOR swizzle) — used for lin1 ----------------
// SCALE: multiply the LN output by dinvp[row] before storing (pre-folds the
// symmetric normalization into the gather input rows).
template <int K, int NT, bool A32, bool LN, bool SCALE>
__global__ __launch_bounds__(256) void gemm_mfma(
    const void* __restrict__ Aptr, const unsigned short* __restrict__ BT,
    const float* __restrict__ bias, const float* __restrict__ gamma,
    const float* __restrict__ beta, const float* __restrict__ dinvp,
    void* __restrict__ Cptr, int M) {
    constexpr int BM = 64, N = NT * 16, NSTEP = K / 32;
    __shared__ unsigned short As[2][BM * 32];
    __shared__ unsigned short Bs[2][N * 32];
    const int tid = threadIdx.x;
    const int wave = tid >> 6, lane = tid & 63;
    const int l15 = lane & 15, quad = lane >> 4;
    const int row0 = blockIdx.x * BM;

    const int sr = tid >> 2, sc = tid & 3;
    const int sswz = sc ^ ((sr >> 2) & 3);
    const bool aok = (row0 + sr) < M;

    const float* A32p = (const float*)Aptr + (size_t)(row0 + sr) * K + sc * 8;
    const unsigned short* A16p = (const unsigned short*)Aptr + (size_t)(row0 + sr) * K + sc * 8;
    const unsigned short* B0p = BT + (size_t)sr * K + sc * 8;
    const unsigned short* B1p = BT + (size_t)(sr + 64) * K + sc * 8;

    float4 pa0, pa1;
    int4 pa16, pb0, pb1;
    if (A32) {
        pa0 = aok ? *(const float4*)(A32p) : make_float4(0.f, 0.f, 0.f, 0.f);
        pa1 = aok ? *(const float4*)(A32p + 4) : make_float4(0.f, 0.f, 0.f, 0.f);
    } else {
        pa16 = aok ? *(const int4*)(A16p) : make_int4(0, 0, 0, 0);
    }
    pb0 = *(const int4*)(B0p);
    if (NT == 8) pb1 = *(const int4*)(B1p);

    f32x4 acc[NT];
#pragma unroll
    for (int ni = 0; ni < NT; ni++) acc[ni] = (f32x4){0.f, 0.f, 0.f, 0.f};

    float bia[NT], gam[NT], bet[NT];
#pragma unroll
    for (int ni = 0; ni < NT; ni++) {
        bia[ni] = bias[ni * 16 + l15];
        if (LN) {
            gam[ni] = gamma[ni * 16 + l15];
            bet[ni] = beta[ni * 16 + l15];
        }
    }

    const int fswz = quad ^ ((l15 >> 2) & 3);
    const int aoff = (wave * 16 + l15) * 32 + fswz * 8;

    for (int step = 0; step < NSTEP; step++) {
        const int buf = step & 1;
        if (A32) {
            int4 w;
            w.x = (int)((unsigned int)bf16r(pa0.x) | ((unsigned int)bf16r(pa0.y) << 16));
            w.y = (int)((unsigned int)bf16r(pa0.z) | ((unsigned int)bf16r(pa0.w) << 16));
            w.z = (int)((unsigned int)bf16r(pa1.x) | ((unsigned int)bf16r(pa1.y) << 16));
            w.w = (int)((unsigned int)bf16r(pa1.z) | ((unsigned int)bf16r(pa1.w) << 16));
            *(int4*)&As[buf][sr * 32 + sswz * 8] = w;
        } else {
            *(int4*)&As[buf][sr * 32 + sswz * 8] = pa16;
        }
        *(int4*)&Bs[buf][sr * 32 + sswz * 8] = pb0;
        if (NT == 8) *(int4*)&Bs[buf][(sr + 64) * 32 + sswz * 8] = pb1;
        __syncthreads();
        if (step + 1 < NSTEP) {
            const int ko = (step + 1) * 32;
            if (A32) {
                pa0 = aok ? *(const float4*)(A32p + ko) : make_float4(0.f, 0.f, 0.f, 0.f);
                pa1 = aok ? *(const float4*)(A32p + ko + 4) : make_float4(0.f, 0.f, 0.f, 0.f);
            } else {
                pa16 = aok ? *(const int4*)(A16p + ko) : make_int4(0, 0, 0, 0);
            }
            pb0 = *(const int4*)(B0p + ko);
            if (NT == 8) pb1 = *(const int4*)(B1p + ko);
        }
        bf16x8 a = *(const bf16x8*)&As[buf][aoff];
#pragma unroll
        for (int ni = 0; ni < NT; ni++) {
            bf16x8 b = *(const bf16x8*)&Bs[buf][(ni * 16 + l15) * 32 + fswz * 8];
            acc[ni] = __builtin_amdgcn_mfma_f32_16x16x32_bf16(a, b, acc[ni], 0, 0, 0);
        }
    }

#pragma unroll
    for (int r = 0; r < 4; r++) {
        int grow = row0 + wave * 16 + quad * 4 + r;
        if (LN) {
            float g[NT];
            float s = 0.f, sq = 0.f;
#pragma unroll
            for (int ni = 0; ni < NT; ni++) {
                float v = gelu_exact(acc[ni][r] + bia[ni]);
                g[ni] = v;
                s += v;
                sq += v * v;
            }
#pragma unroll
            for (int m = 1; m < 16; m <<= 1) {
                s += __shfl_xor(s, m);
                sq += __shfl_xor(sq, m);
            }
            float mu = s * (1.0f / N);
            float var = sq * (1.0f / N) - mu * mu;
            float rs = rsqrtf(var + 1e-5f);
            if (grow < M) {
                float dv = 1.0f;
                if (SCALE) dv = dinvp[grow];
                unsigned short* C = (unsigned short*)Cptr;
#pragma unroll
                for (int ni = 0; ni < NT; ni++) {
                    float o = (g[ni] - mu) * rs * gam[ni] + bet[ni];
                    if (SCALE) o *= dv;
                    C[(size_t)grow * N + ni * 16 + l15] = bf16r(o);
                }
            }
        } else {
            if (grow < M) {
                float* C = (float*)Cptr;
#pragma unroll
                for (int ni = 0; ni < NT; ni++)
                    C[(size_t)grow * N + ni * 16 + l15] = acc[ni][r] + bia[ni];
            }
        }
    }
}

// ---------------- fused GEMM2+GEMM3: out = (LN(GELU(A*Wc+bc)))*W2 + b2 ----------------
// K=128/64 are small: stage A-tile, Wc, W2 fully in LDS once (80 KB, 2 blocks/CU).
// The intermediate h tile is rounded to bf16 into LDS (same values as the old
// hB global round-trip), then consumed as the A-operand of the second GEMM.
// Chunk-major LDS layout [step][row][32] with the verified XOR swizzle
// (slot ^ ((row>>2)&3)), identical to gemm_mfma's As/Bs pattern.
__global__ __launch_bounds__(256) void gemm23(
    const unsigned short* __restrict__ A,    // hA [M][128] bf16
    const unsigned short* __restrict__ WcT,  // [128][128] bf16, n-major
    const unsigned short* __restrict__ W2T,  // [64][128] bf16, n-major
    const float* __restrict__ bc, const float* __restrict__ g2,
    const float* __restrict__ be2, const float* __restrict__ b2,
    float* __restrict__ out, int M) {
    __shared__ unsigned short As[4 * 64 * 32];   // 16 KB
    __shared__ unsigned short Bs[4 * 128 * 32];  // 32 KB (Wc)
    __shared__ unsigned short Ws[4 * 64 * 32];   // 16 KB (W2)
    __shared__ unsigned short Hs[4 * 64 * 32];   // 16 KB (h tile)
    const int tid = threadIdx.x;
    const int wave = tid >> 6, lane = tid & 63;
    const int l15 = lane & 15, quad = lane >> 4;
    const int row0 = blockIdx.x * 64;

    const int sr = tid >> 2, sc = tid & 3;
    const int ssw = sc ^ ((sr >> 2) & 3);
    const bool aok = (row0 + sr) < M;
    const unsigned short* Ap = A + (size_t)(row0 + sr) * HID + sc * 8;

#pragma unroll
    for (int st = 0; st < 4; st++) {
        int4 va = aok ? *(const int4*)(Ap + st * 32) : make_int4(0, 0, 0, 0);
        *(int4*)&As[((st * 64) + sr) * 32 + ssw * 8] = va;
        int4 vb0 = *(const int4*)(WcT + (size_t)sr * HID + st * 32 + sc * 8);
        int4 vb1 = *(const int4*)(WcT + (size_t)(sr + 64) * HID + st * 32 + sc * 8);
        *(int4*)&Bs[((st * 128) + sr) * 32 + ssw * 8] = vb0;
        *(int4*)&Bs[((st * 128) + sr + 64) * 32 + ssw * 8] = vb1;  // ((sr+64)>>2)&3 == (sr>>2)&3
        int4 vw = *(const int4*)(W2T + (size_t)sr * HID + st * 32 + sc * 8);
        *(int4*)&Ws[((st * 64) + sr) * 32 + ssw * 8] = vw;
    }

    float bia[8], gam[8], bet[8];
#pragma unroll
    for (int ni = 0; ni < 8; ni++) {
        bia[ni] = bc[ni * 16 + l15];
        gam[ni] = g2[ni * 16 + l15];
        bet[ni] = be2[ni * 16 + l15];
    }
    float b2v[4];
#pragma unroll
    for (int ni = 0; ni < 4; ni++) b2v[ni] = b2[ni * 16 + l15];

    __syncthreads();

    // ---- phase 1: acc = A * Wc ----
    const int fsw = quad ^ ((l15 >> 2) & 3);
    f32x4 acc[8];
#pragma unroll
    for (int ni = 0; ni < 8; ni++) acc[ni] = (f32x4){0.f, 0.f, 0.f, 0.f};
#pragma unroll
    for (int st = 0; st < 4; st++) {
        bf16x8 a = *(const bf16x8*)&As[((st * 64) + wave * 16 + l15) * 32 + fsw * 8];
#pragma unroll
        for (int ni = 0; ni < 8; ni++) {
            bf16x8 b = *(const bf16x8*)&Bs[((st * 128) + ni * 16 + l15) * 32 + fsw * 8];
            acc[ni] = __builtin_amdgcn_mfma_f32_16x16x32_bf16(a, b, acc[ni], 0, 0, 0);
        }
    }

    // ---- phase 2: gelu+LN epilogue -> Hs (bf16, swizzled) ----
#pragma unroll
    for (int r = 0; r < 4; r++) {
        const int lrow = wave * 16 + quad * 4 + r;  // local row 0..63
        float g[8];
        float s = 0.f, sq = 0.f;
#pragma unroll
        for (int ni = 0; ni < 8; ni++) {
            float v = gelu_exact(acc[ni][r] + bia[ni]);
            g[ni] = v;
            s += v;
            sq += v * v;
        }
#pragma unroll
        for (int m = 1; m < 16; m <<= 1) {
            s += __shfl_xor(s, m);
            sq += __shfl_xor(sq, m);
        }
        float mu = s * (1.0f / HID);
        float var = sq * (1.0f / HID) - mu * mu;
        float rs = rsqrtf(var + 1e-5f);
        const int key = (lrow >> 2) & 3;
#pragma unroll
        for (int ni = 0; ni < 8; ni++) {
            float o = (g[ni] - mu) * rs * gam[ni] + bet[ni];
            const int col = ni * 16 + l15;
            const int chunk = col >> 5, cc = col & 31;
            const int slot = (cc >> 3) ^ key;
            Hs[((chunk * 64) + lrow) * 32 + slot * 8 + (cc & 7)] = bf16r(o);
        }
    }
    __syncthreads();

    // ---- phase 3: out = Hs * W2 + b2 ----
    f32x4 acc2[4];
#pragma unroll
    for (int ni = 0; ni < 4; ni++) acc2[ni] = (f32x4){0.f, 0.f, 0.f, 0.f};
#pragma unroll
    for (int st = 0; st < 4; st++) {
        bf16x8 a = *(const bf16x8*)&Hs[((st * 64) + wave * 16 + l15) * 32 + fsw * 8];
#pragma unroll
        for (int ni = 0; ni < 4; ni++) {
            bf16x8 b = *(const bf16x8*)&Ws[((st * 64) + ni * 16 + l15) * 32 + fsw * 8];
            acc2[ni] = __builtin_amdgcn_mfma_f32_16x16x32_bf16(a, b, acc2[ni], 0, 0, 0);
        }
    }
#pragma unroll
    for (int r = 0; r < 4; r++) {
        const int grow = row0 + wave * 16 + quad * 4 + r;
        if (grow < M) {
#pragma unroll
            for (int ni = 0; ni < 4; ni++)
                out[(size_t)grow * OUT_CH + ni * 16 + l15] = acc2[ni][r] + b2v[ni];
        }
    }
}

// ---------------- propagation: add-only CSR gather on pre-scaled bf16 rows ----------------
// Input rows are h' = dinv[j]*h[j].  out[i] = scale(i) * (h'[i] + sum_{j in N(i)} h'[j])
// where scale = dinv^2 for hop1 (output stays pre-scaled for hop2) and dinv for hop2.
__global__ __launch_bounds__(256) void sgc_gather_bf16(const unsigned short* __restrict__ hin,
                                                       unsigned short* __restrict__ hout,
                                                       const int* __restrict__ rowptr,
                                                       const int* __restrict__ eadj,
                                                       const float* __restrict__ dinv,
                                                       int n, int pw) {
    int row = __builtin_amdgcn_readfirstlane(blockIdx.x * 4 + (threadIdx.x >> 6));
    if (row >= n) return;
    const int lane = threadIdx.x & 63;
    const unsigned int* __restrict__ rows = (const unsigned int*)hin;
    unsigned int u = rows[(size_t)row * 64 + lane];
    float ax = bf16f((unsigned short)(u & 0xffff));
    float ay = bf16f((unsigned short)(u >> 16));
    int j = rowptr[row];
    const int end = rowptr[row + 1];
    for (; j + 7 < end; j += 8) {
        int s[8];
#pragma unroll
        for (int t = 0; t < 8; t++) s[t] = __builtin_amdgcn_readfirstlane(eadj[j + t]);
        unsigned int uu[8];
#pragma unroll
        for (int t = 0; t < 8; t++) uu[t] = rows[(size_t)s[t] * 64 + lane];
#pragma unroll
        for (int t = 0; t < 8; t++) {
            ax += bf16f((unsigned short)(uu[t] & 0xffff));
            ay += bf16f((unsigned short)(uu[t] >> 16));
        }
    }
    for (; j < end; j++) {
        int s0 = __builtin_amdgcn_readfirstlane(eadj[j]);
        unsigned int u0 = rows[(size_t)s0 * 64 + lane];
        ax += bf16f((unsigned short)(u0 & 0xffff));
        ay += bf16f((unsigned short)(u0 >> 16));
    }
    float di = dinv[row];
    float sc = (pw == 2) ? di * di : di;
    ax *= sc;
    ay *= sc;
    unsigned int o = (unsigned int)bf16r(ax) | ((unsigned int)bf16r(ay) << 16);
    *(unsigned int*)(hout + (size_t)row * HID + lane * 2) = o;
}

extern "C" void kernel_launch(void* const* d_in, const int* in_sizes, int n_in,
                              void* d_out, int out_size, void* d_ws, size_t ws_size,
                              hipStream_t stream) {
    const float* x   = (const float*)d_in[0];
    const int*   ei  = (const int*)d_in[1];
    const float* W1  = (const float*)d_in[2];
    const float* b1  = (const float*)d_in[3];
    const float* g1  = (const float*)d_in[4];
    const float* be1 = (const float*)d_in[5];
    const float* Wc  = (const float*)d_in[6];
    const float* bc  = (const float*)d_in[7];
    const float* g2  = (const float*)d_in[8];
    const float* be2 = (const float*)d_in[9];
    const float* W2  = (const float*)d_in[10];
    const float* b2  = (const float*)d_in[11];
    float* out = (float*)d_out;

    const int N = in_sizes[0] / IN_CH;  // 100000
    const int E = in_sizes[1] / 2;      // 1600000
    const int* src = ei;
    const int* dst = ei + E;

    char* ws = (char*)d_ws;
    size_t off = 0;
    auto alloc = [&](size_t bytes) {
        void* p = ws + off;
        off = (off + bytes + 255) & ~(size_t)255;
        return p;
    };
    float* dinv   = (float*)alloc((size_t)N * 4);
    int*   rowptr = (int*)alloc((size_t)(N + 1) * 4);
    int*   bcnt   = (int*)alloc((size_t)(NBUCK + 1) * 4);
    int*   bbase  = (int*)alloc((size_t)(NBUCK + 1) * 4);
    int*   bcur   = (int*)alloc((size_t)(NBUCK + 1) * 4);
    unsigned int* ebuf = (unsigned int*)alloc((size_t)E * 4);
    int*   eadj   = (int*)alloc((size_t)E * 4);
    unsigned short* W1T = (unsigned short*)alloc((size_t)HID * IN_CH * 2);
    unsigned short* WcT = (unsigned short*)alloc((size_t)HID * HID * 2);
    unsigned short* W2T = (unsigned short*)alloc((size_t)OUT_CH * HID * 2);
    unsigned short* hA  = (unsigned short*)alloc((size_t)N * HID * 2);
    unsigned short* hB  = (unsigned short*)alloc((size_t)N * HID * 2);

    const int B = 256;
    const int eblk16 = (E + 4095) / 4096;  // 391

    // weight prep + bcnt zero (one launch, runs first)
    const int convtot = IN_CH * HID + HID * HID + HID * OUT_CH;
    conv_all<<<(convtot + 255) / 256, B, 0, stream>>>(W1, Wc, W2, W1T, WcT, W2T, bcnt);

    // bucketed CSR build (+ dinv, rowptr)
    bhist<<<eblk16, B, 0, stream>>>(dst, bcnt, E);
    bscan<<<1, 512, 0, stream>>>(bcnt, bbase, bcur, rowptr, E);
    binA<<<eblk16, B, 0, stream>>>(src, dst, bcur, ebuf, E);
    binB<<<NBUCK, B, 0, stream>>>(ebuf, bbase, rowptr, eadj, dinv);

    const int gblk = (N + 63) / 64;  // 1563
    // lin1 + gelu + LN + dinv-prescale -> hA (bf16, rows = dinv*h)
    gemm_mfma<IN_CH, 8, true, true, true><<<gblk, B, 0, stream>>>(x, W1T, b1, g1, be1, dinv, hA, N);
    // hops (add-only): hA -> hB (x dinv^2, stays pre-scaled) -> hA (x dinv, unscaled h2)
    sgc_gather_bf16<<<(N + 3) / 4, B, 0, stream>>>(hA, hB, rowptr, eadj, dinv, N, 2);
    sgc_gather_bf16<<<(N + 3) / 4, B, 0, stream>>>(hB, hA, rowptr, eadj, dinv, N, 1);
    // fused: Wc+gelu+LN then W2+bias -> out (fp32)
    gemm23<<<gblk, B, 0, stream>>>(hA, WcT, W2T, bc, g2, be2, b2, out, N);
}